// Round 1
// baseline (1141.368 us; speedup 1.0000x reference)
//
#include <hip/hip_runtime.h>
#include <hip/hip_bf16.h>

#define DD 128

typedef short bf16x8 __attribute__((ext_vector_type(8)));
typedef float f32x4 __attribute__((ext_vector_type(4)));

__device__ __forceinline__ unsigned short f2b(float f) {
  unsigned int u = __float_as_uint(f);
  u = u + 0x7FFFu + ((u >> 16) & 1u);
  return (unsigned short)(u >> 16);
}

// ---------------- per-node in-degree ----------------
__global__ void count_kernel(const int* __restrict__ ei, float* __restrict__ cnt, int E) {
  int i = blockIdx.x * blockDim.x + threadIdx.x;
  if (i < E) atomicAdd(&cnt[ei[E + i]], 1.0f);
}

// ---------------- edge MLP + scatter-add ----------------
__global__ __launch_bounds__(256, 1) void edge_mlp_kernel(
    const float* __restrict__ x,
    const int* __restrict__ ei,       // [2][E]
    const float* __restrict__ ea,     // [E][128]
    const float* __restrict__ We1,    // [384][128]
    const float* __restrict__ be1,
    const float* __restrict__ We2,    // [128][128]
    const float* __restrict__ be2,
    float* __restrict__ e_out,        // [E][128]
    float* __restrict__ agg,          // [N][128] (zeroed)
    int E)
{
  __shared__ __align__(16) unsigned short A_lds[64][392];  // 64 x 384 bf16, +8 pad
  __shared__ __align__(16) unsigned short h_lds[64][136];  // 64 x 128 bf16, +8 pad

  const int tid  = threadIdx.x;
  const int wv   = tid >> 6;
  const int lane = tid & 63;
  const int lg   = lane >> 4;
  const int lm   = lane & 15;

  // ---- load weight fragments into registers (once per block) ----
  bf16x8 w1f[12][2];
  bf16x8 w2f[4][2];
  float b1[2], b2[2];
#pragma unroll
  for (int nf = 0; nf < 2; ++nf) {
    const int n = wv * 32 + nf * 16 + lm;
    b1[nf] = be1[n];
    b2[nf] = be2[n];
#pragma unroll
    for (int kb = 0; kb < 12; ++kb) {
      bf16x8 f;
#pragma unroll
      for (int j = 0; j < 8; ++j)
        f[j] = (short)f2b(We1[(kb * 32 + lg * 8 + j) * DD + n]);
      w1f[kb][nf] = f;
    }
#pragma unroll
    for (int kb = 0; kb < 4; ++kb) {
      bf16x8 f;
#pragma unroll
      for (int j = 0; j < 8; ++j)
        f[j] = (short)f2b(We2[(kb * 32 + lg * 8 + j) * DD + n]);
      w2f[kb][nf] = f;
    }
  }

  const int ntiles = (E + 63) >> 6;
  for (int tile = blockIdx.x; tile < ntiles; tile += gridDim.x) {
    const int ebase = tile << 6;
    __syncthreads();  // protect LDS from previous iteration's readers

    // ---- stage A = [x[src] | x[dest] | ea] as bf16 into LDS ----
    for (int q = tid; q < 64 * 96; q += 256) {
      const int e = q / 96;
      const int r = q - e * 96;
      const int s = r >> 5;        // 0: x[src], 1: x[dest], 2: edge_attr
      const int c = r & 31;        // float4 chunk within 128 cols
      int ge = ebase + e;
      if (ge >= E) ge = E - 1;
      const float* p;
      if (s == 0)      p = x + (long long)ei[ge] * DD;
      else if (s == 1) p = x + (long long)ei[E + ge] * DD;
      else             p = ea + (long long)ge * DD;
      const float4 v = *reinterpret_cast<const float4*>(p + (c << 2));
      unsigned short* dst = &A_lds[e][(s << 7) + (c << 2)];
      dst[0] = f2b(v.x); dst[1] = f2b(v.y); dst[2] = f2b(v.z); dst[3] = f2b(v.w);
    }
    __syncthreads();

    // ---- layer 1: h = relu(A @ We1 + be1) ----
    f32x4 acc[4][2];
#pragma unroll
    for (int mf = 0; mf < 4; ++mf)
#pragma unroll
      for (int nf = 0; nf < 2; ++nf)
        acc[mf][nf] = (f32x4){0.f, 0.f, 0.f, 0.f};

#pragma unroll
    for (int kb = 0; kb < 12; ++kb) {
      bf16x8 a[4];
#pragma unroll
      for (int mf = 0; mf < 4; ++mf)
        a[mf] = *reinterpret_cast<const bf16x8*>(&A_lds[mf * 16 + lm][kb * 32 + lg * 8]);
#pragma unroll
      for (int mf = 0; mf < 4; ++mf)
#pragma unroll
        for (int nf = 0; nf < 2; ++nf)
          acc[mf][nf] = __builtin_amdgcn_mfma_f32_16x16x32_bf16(a[mf], w1f[kb][nf], acc[mf][nf], 0, 0, 0);
    }

#pragma unroll
    for (int mf = 0; mf < 4; ++mf)
#pragma unroll
      for (int nf = 0; nf < 2; ++nf)
#pragma unroll
        for (int rg = 0; rg < 4; ++rg) {
          const int m = mf * 16 + lg * 4 + rg;
          const int n = wv * 32 + nf * 16 + lm;
          float v = acc[mf][nf][rg] + b1[nf];
          h_lds[m][n] = f2b(v > 0.f ? v : 0.f);
        }
    __syncthreads();

    // ---- layer 2: e = h @ We2 + be2 ----
    f32x4 acc2[4][2];
#pragma unroll
    for (int mf = 0; mf < 4; ++mf)
#pragma unroll
      for (int nf = 0; nf < 2; ++nf)
        acc2[mf][nf] = (f32x4){0.f, 0.f, 0.f, 0.f};

#pragma unroll
    for (int kb = 0; kb < 4; ++kb) {
      bf16x8 a[4];
#pragma unroll
      for (int mf = 0; mf < 4; ++mf)
        a[mf] = *reinterpret_cast<const bf16x8*>(&h_lds[mf * 16 + lm][kb * 32 + lg * 8]);
#pragma unroll
      for (int mf = 0; mf < 4; ++mf)
#pragma unroll
        for (int nf = 0; nf < 2; ++nf)
          acc2[mf][nf] = __builtin_amdgcn_mfma_f32_16x16x32_bf16(a[mf], w2f[kb][nf], acc2[mf][nf], 0, 0, 0);
    }

    // ---- epilogue: write e, scatter-add into agg ----
#pragma unroll
    for (int mf = 0; mf < 4; ++mf)
#pragma unroll
      for (int rg = 0; rg < 4; ++rg) {
        const int m  = mf * 16 + lg * 4 + rg;
        const int gm = ebase + m;
        if (gm < E) {
          const long long dn = (long long)ei[E + gm];
#pragma unroll
          for (int nf = 0; nf < 2; ++nf) {
            const int n = wv * 32 + nf * 16 + lm;
            const float v = acc2[mf][nf][rg] + b2[nf];
            e_out[(long long)gm * DD + n] = v;
            atomicAdd(&agg[dn * DD + n], v);
          }
        }
      }
  }
}

// ---------------- node MLP ----------------
__global__ __launch_bounds__(256, 1) void node_mlp_kernel(
    const float* __restrict__ x,
    const float* __restrict__ Wn1,   // [256][128]
    const float* __restrict__ bn1,
    const float* __restrict__ Wn2,   // [128][128]
    const float* __restrict__ bn2,
    const float* __restrict__ cnt,   // [N]
    float* __restrict__ xout,        // in: agg sums, out: x_out
    int N)
{
  __shared__ __align__(16) unsigned short A_lds[64][264];  // 64 x 256 bf16, +8 pad
  __shared__ __align__(16) unsigned short h_lds[64][136];

  const int tid  = threadIdx.x;
  const int wv   = tid >> 6;
  const int lane = tid & 63;
  const int lg   = lane >> 4;
  const int lm   = lane & 15;

  bf16x8 w1f[8][2];
  bf16x8 w2f[4][2];
  float b1[2], b2[2];
#pragma unroll
  for (int nf = 0; nf < 2; ++nf) {
    const int n = wv * 32 + nf * 16 + lm;
    b1[nf] = bn1[n];
    b2[nf] = bn2[n];
#pragma unroll
    for (int kb = 0; kb < 8; ++kb) {
      bf16x8 f;
#pragma unroll
      for (int j = 0; j < 8; ++j)
        f[j] = (short)f2b(Wn1[(kb * 32 + lg * 8 + j) * DD + n]);
      w1f[kb][nf] = f;
    }
#pragma unroll
    for (int kb = 0; kb < 4; ++kb) {
      bf16x8 f;
#pragma unroll
      for (int j = 0; j < 8; ++j)
        f[j] = (short)f2b(Wn2[(kb * 32 + lg * 8 + j) * DD + n]);
      w2f[kb][nf] = f;
    }
  }

  const int ntiles = (N + 63) >> 6;
  for (int tile = blockIdx.x; tile < ntiles; tile += gridDim.x) {
    const int nbase = tile << 6;
    __syncthreads();

    // ---- stage A = [x | agg/cnt] as bf16 ----
    for (int q = tid; q < 64 * 64; q += 256) {
      const int r = q >> 6;
      const int c = q & 63;       // float4 chunk within 256 cols
      int gr = nbase + r;
      const bool ok = gr < N;
      if (!ok) gr = 0;
      float4 v;
      if (c < 32) {
        v = *reinterpret_cast<const float4*>(x + (long long)gr * DD + (c << 2));
      } else {
        v = *reinterpret_cast<const float4*>(xout + (long long)gr * DD + ((c - 32) << 2));
        const float ic = 1.0f / fmaxf(cnt[gr], 1.0f);
        v.x *= ic; v.y *= ic; v.z *= ic; v.w *= ic;
      }
      unsigned short* dst = &A_lds[r][c << 2];
      dst[0] = f2b(v.x); dst[1] = f2b(v.y); dst[2] = f2b(v.z); dst[3] = f2b(v.w);
    }
    __syncthreads();

    // ---- layer 1 ----
    f32x4 acc[4][2];
#pragma unroll
    for (int mf = 0; mf < 4; ++mf)
#pragma unroll
      for (int nf = 0; nf < 2; ++nf)
        acc[mf][nf] = (f32x4){0.f, 0.f, 0.f, 0.f};

#pragma unroll
    for (int kb = 0; kb < 8; ++kb) {
      bf16x8 a[4];
#pragma unroll
      for (int mf = 0; mf < 4; ++mf)
        a[mf] = *reinterpret_cast<const bf16x8*>(&A_lds[mf * 16 + lm][kb * 32 + lg * 8]);
#pragma unroll
      for (int mf = 0; mf < 4; ++mf)
#pragma unroll
        for (int nf = 0; nf < 2; ++nf)
          acc[mf][nf] = __builtin_amdgcn_mfma_f32_16x16x32_bf16(a[mf], w1f[kb][nf], acc[mf][nf], 0, 0, 0);
    }

#pragma unroll
    for (int mf = 0; mf < 4; ++mf)
#pragma unroll
      for (int nf = 0; nf < 2; ++nf)
#pragma unroll
        for (int rg = 0; rg < 4; ++rg) {
          const int m = mf * 16 + lg * 4 + rg;
          const int n = wv * 32 + nf * 16 + lm;
          float v = acc[mf][nf][rg] + b1[nf];
          h_lds[m][n] = f2b(v > 0.f ? v : 0.f);
        }
    __syncthreads();

    // ---- layer 2 ----
    f32x4 acc2[4][2];
#pragma unroll
    for (int mf = 0; mf < 4; ++mf)
#pragma unroll
      for (int nf = 0; nf < 2; ++nf)
        acc2[mf][nf] = (f32x4){0.f, 0.f, 0.f, 0.f};

#pragma unroll
    for (int kb = 0; kb < 4; ++kb) {
      bf16x8 a[4];
#pragma unroll
      for (int mf = 0; mf < 4; ++mf)
        a[mf] = *reinterpret_cast<const bf16x8*>(&h_lds[mf * 16 + lm][kb * 32 + lg * 8]);
#pragma unroll
      for (int mf = 0; mf < 4; ++mf)
#pragma unroll
        for (int nf = 0; nf < 2; ++nf)
          acc2[mf][nf] = __builtin_amdgcn_mfma_f32_16x16x32_bf16(a[mf], w2f[kb][nf], acc2[mf][nf], 0, 0, 0);
    }

#pragma unroll
    for (int mf = 0; mf < 4; ++mf)
#pragma unroll
      for (int rg = 0; rg < 4; ++rg) {
        const int m  = mf * 16 + lg * 4 + rg;
        const int gm = nbase + m;
        if (gm < N) {
#pragma unroll
          for (int nf = 0; nf < 2; ++nf) {
            const int n = wv * 32 + nf * 16 + lm;
            xout[(long long)gm * DD + n] = acc2[mf][nf][rg] + b2[nf];
          }
        }
      }
  }
}

extern "C" void kernel_launch(void* const* d_in, const int* in_sizes, int n_in,
                              void* d_out, int out_size, void* d_ws, size_t ws_size,
                              hipStream_t stream) {
  const float* x   = (const float*)d_in[0];
  const int*   ei  = (const int*)d_in[1];
  const float* ea  = (const float*)d_in[2];
  const float* We1 = (const float*)d_in[3];
  const float* be1 = (const float*)d_in[4];
  const float* We2 = (const float*)d_in[5];
  const float* be2 = (const float*)d_in[6];
  const float* Wn1 = (const float*)d_in[7];
  const float* bn1 = (const float*)d_in[8];
  const float* Wn2 = (const float*)d_in[9];
  const float* bn2 = (const float*)d_in[10];

  const int N = in_sizes[0] / DD;   // 50000
  const int E = in_sizes[2] / DD;   // 600000

  float* out   = (float*)d_out;
  float* xout  = out;                        // first output region; doubles as agg scratch
  float* e_out = out + (size_t)N * DD;       // second output region
  float* cnt   = (float*)d_ws;               // N floats

  hipMemsetAsync(xout, 0, (size_t)N * DD * sizeof(float), stream);
  hipMemsetAsync(cnt, 0, (size_t)N * sizeof(float), stream);

  count_kernel<<<(E + 255) / 256, 256, 0, stream>>>(ei, cnt, E);

  edge_mlp_kernel<<<1024, 256, 0, stream>>>(x, ei, ea, We1, be1, We2, be2,
                                            e_out, xout, E);

  const int node_tiles = (N + 63) / 64;
  node_mlp_kernel<<<node_tiles, 256, 0, stream>>>(x, Wn1, bn1, Wn2, bn2,
                                                  cnt, xout, N);
}

// Round 2
// 633.960 us; speedup vs baseline: 1.8004x; 1.8004x over previous
//
#include <hip/hip_runtime.h>
#include <hip/hip_bf16.h>

#define DD 128

typedef short bf16x8 __attribute__((ext_vector_type(8)));
typedef float f32x4 __attribute__((ext_vector_type(4)));

__device__ __forceinline__ unsigned short f2b(float f) {
  unsigned int u = __float_as_uint(f);
  u = u + 0x7FFFu + ((u >> 16) & 1u);
  return (unsigned short)(u >> 16);
}

// ---------------- per-node in-degree (int) ----------------
__global__ void count_kernel(const int* __restrict__ ei, int* __restrict__ cnt, int E) {
  int i = blockIdx.x * blockDim.x + threadIdx.x;
  if (i < E) atomicAdd(&cnt[ei[E + i]], 1);
}

// ---------------- prefix scan (3 kernels) ----------------
// scan_a: per-1024-chunk exclusive scan; writes chunk totals to bsum
__global__ __launch_bounds__(256) void scan_a(const int* __restrict__ cnt,
                                              int* __restrict__ off,
                                              int* __restrict__ bsum, int N) {
  __shared__ int wsum[4];
  const int t = threadIdx.x;
  const int base = blockIdx.x * 1024;
  const int i0 = base + t * 4;
  int4 v = {0, 0, 0, 0};
  if (i0 + 3 < N) v = *reinterpret_cast<const int4*>(cnt + i0);
  else {
    if (i0 < N)     v.x = cnt[i0];
    if (i0 + 1 < N) v.y = cnt[i0 + 1];
    if (i0 + 2 < N) v.z = cnt[i0 + 2];
    if (i0 + 3 < N) v.w = cnt[i0 + 3];
  }
  const int s1 = v.x, s2 = s1 + v.y, s3 = s2 + v.z, tot = s3 + v.w;
  const int lane = t & 63, wv = t >> 6;
  int sc = tot;
#pragma unroll
  for (int d = 1; d < 64; d <<= 1) {
    int u = __shfl_up(sc, d);
    if (lane >= d) sc += u;
  }
  if (lane == 63) wsum[wv] = sc;
  __syncthreads();
  int wpre = 0;
  for (int w = 0; w < wv; ++w) wpre += wsum[w];
  const int excl = wpre + sc - tot;
  if (i0 < N)     off[i0]     = excl;
  if (i0 + 1 < N) off[i0 + 1] = excl + s1;
  if (i0 + 2 < N) off[i0 + 2] = excl + s2;
  if (i0 + 3 < N) off[i0 + 3] = excl + s3;
  if (t == 255) bsum[blockIdx.x] = wpre + sc;
}

// scan_b: exclusive scan of block sums (B <= 64)
__global__ void scan_b(int* __restrict__ bsum, int B) {
  const int t = threadIdx.x;
  const int v0 = (t < B) ? bsum[t] : 0;
  int v = v0;
#pragma unroll
  for (int d = 1; d < 64; d <<= 1) {
    int u = __shfl_up(v, d);
    if (t >= d) v += u;
  }
  if (t < B) bsum[t] = v - v0;
}

// scan_c: add block prefix; copy to cursor; write off[N]=E
__global__ __launch_bounds__(256) void scan_c(int* __restrict__ off, int* __restrict__ cur,
                                              const int* __restrict__ bsum, int N, int E) {
  const int t = threadIdx.x;
  const int add = bsum[blockIdx.x];
  const int i0 = blockIdx.x * 1024 + t * 4;
#pragma unroll
  for (int k = 0; k < 4; ++k) {
    const int i = i0 + k;
    if (i < N) {
      const int o = off[i] + add;
      off[i] = o;
      cur[i] = o;
    }
  }
  if (blockIdx.x == 0 && t == 0) off[N] = E;
}

// fill: counting-sort edge ids by dest
__global__ void fill_kernel(const int* __restrict__ ei, int* __restrict__ cur,
                            int* __restrict__ perm, int E) {
  int i = blockIdx.x * blockDim.x + threadIdx.x;
  if (i < E) {
    const int d = ei[E + i];
    const int pos = atomicAdd(&cur[d], 1);
    perm[pos] = i;
  }
}

// ---------------- edge MLP (no atomics) ----------------
__global__ __launch_bounds__(256, 2) void edge_mlp_kernel(
    const float* __restrict__ x,
    const int* __restrict__ ei,       // [2][E]
    const float* __restrict__ ea,     // [E][128]
    const float* __restrict__ We1,    // [384][128]
    const float* __restrict__ be1,
    const float* __restrict__ We2,    // [128][128]
    const float* __restrict__ be2,
    float* __restrict__ e_out,        // [E][128]
    int E)
{
  __shared__ __align__(16) unsigned short A_lds[64][392];
  __shared__ __align__(16) unsigned short h_lds[64][136];
  __shared__ int srcs[64], dsts[64];

  const int tid  = threadIdx.x;
  const int wv   = tid >> 6;
  const int lane = tid & 63;
  const int lg   = lane >> 4;
  const int lm   = lane & 15;

  // weight fragments in registers (reused across tiles)
  bf16x8 w1f[12][2];
  bf16x8 w2f[4][2];
  float b1[2], b2[2];
#pragma unroll
  for (int nf = 0; nf < 2; ++nf) {
    const int n = wv * 32 + nf * 16 + lm;
    b1[nf] = be1[n];
    b2[nf] = be2[n];
#pragma unroll
    for (int kb = 0; kb < 12; ++kb) {
      bf16x8 f;
#pragma unroll
      for (int j = 0; j < 8; ++j)
        f[j] = (short)f2b(We1[(kb * 32 + lg * 8 + j) * DD + n]);
      w1f[kb][nf] = f;
    }
#pragma unroll
    for (int kb = 0; kb < 4; ++kb) {
      bf16x8 f;
#pragma unroll
      for (int j = 0; j < 8; ++j)
        f[j] = (short)f2b(We2[(kb * 32 + lg * 8 + j) * DD + n]);
      w2f[kb][nf] = f;
    }
  }

  const int ntiles = (E + 63) >> 6;
  for (int tile = blockIdx.x; tile < ntiles; tile += gridDim.x) {
    const int ebase = tile << 6;
    __syncthreads();  // previous iteration's h_lds readers done

    // ---- preload tile indices ----
    if (tid < 64) {
      int ge = ebase + tid; if (ge >= E) ge = E - 1;
      srcs[tid] = ei[ge];
    } else if (tid < 128) {
      int ge = ebase + tid - 64; if (ge >= E) ge = E - 1;
      dsts[tid - 64] = ei[E + ge];
    }
    __syncthreads();

    // ---- gather A = [x[src] | x[dest] | ea] -> bf16 LDS, pipelined ----
#pragma unroll
    for (int half = 0; half < 2; ++half) {
      float4 vbuf[12];
      int eidx[12], ridx[12];
#pragma unroll
      for (int it = 0; it < 12; ++it) {
        const int q = tid + (half * 12 + it) * 256;
        const int e = q / 96;
        const int r = q - e * 96;
        eidx[it] = e; ridx[it] = r;
        const int s = r >> 5;
        const int c = r & 31;
        const float* p;
        if (s == 0)      p = x + (long long)srcs[e] * DD;
        else if (s == 1) p = x + (long long)dsts[e] * DD;
        else {
          int ge = ebase + e; if (ge >= E) ge = E - 1;
          p = ea + (long long)ge * DD;
        }
        vbuf[it] = *reinterpret_cast<const float4*>(p + (c << 2));
      }
#pragma unroll
      for (int it = 0; it < 12; ++it) {
        const int s = ridx[it] >> 5;
        const int c = ridx[it] & 31;
        unsigned short* dst = &A_lds[eidx[it]][(s << 7) + (c << 2)];
        const float4 v = vbuf[it];
        dst[0] = f2b(v.x); dst[1] = f2b(v.y); dst[2] = f2b(v.z); dst[3] = f2b(v.w);
      }
    }
    __syncthreads();

    // ---- layer 1: h = relu(A @ We1 + be1) ----
    f32x4 acc[4][2];
#pragma unroll
    for (int mf = 0; mf < 4; ++mf)
#pragma unroll
      for (int nf = 0; nf < 2; ++nf)
        acc[mf][nf] = (f32x4){0.f, 0.f, 0.f, 0.f};

#pragma unroll
    for (int kb = 0; kb < 12; ++kb) {
      bf16x8 a[4];
#pragma unroll
      for (int mf = 0; mf < 4; ++mf)
        a[mf] = *reinterpret_cast<const bf16x8*>(&A_lds[mf * 16 + lm][kb * 32 + lg * 8]);
#pragma unroll
      for (int mf = 0; mf < 4; ++mf)
#pragma unroll
        for (int nf = 0; nf < 2; ++nf)
          acc[mf][nf] = __builtin_amdgcn_mfma_f32_16x16x32_bf16(a[mf], w1f[kb][nf], acc[mf][nf], 0, 0, 0);
    }

#pragma unroll
    for (int mf = 0; mf < 4; ++mf)
#pragma unroll
      for (int nf = 0; nf < 2; ++nf)
#pragma unroll
        for (int rg = 0; rg < 4; ++rg) {
          const int m = mf * 16 + lg * 4 + rg;
          const int n = wv * 32 + nf * 16 + lm;
          float v = acc[mf][nf][rg] + b1[nf];
          h_lds[m][n] = f2b(v > 0.f ? v : 0.f);
        }
    __syncthreads();

    // ---- layer 2: e = h @ We2 + be2 ----
    f32x4 acc2[4][2];
#pragma unroll
    for (int mf = 0; mf < 4; ++mf)
#pragma unroll
      for (int nf = 0; nf < 2; ++nf)
        acc2[mf][nf] = (f32x4){0.f, 0.f, 0.f, 0.f};

#pragma unroll
    for (int kb = 0; kb < 4; ++kb) {
      bf16x8 a[4];
#pragma unroll
      for (int mf = 0; mf < 4; ++mf)
        a[mf] = *reinterpret_cast<const bf16x8*>(&h_lds[mf * 16 + lm][kb * 32 + lg * 8]);
#pragma unroll
      for (int mf = 0; mf < 4; ++mf)
#pragma unroll
        for (int nf = 0; nf < 2; ++nf)
          acc2[mf][nf] = __builtin_amdgcn_mfma_f32_16x16x32_bf16(a[mf], w2f[kb][nf], acc2[mf][nf], 0, 0, 0);
    }

    // ---- epilogue: write e only ----
#pragma unroll
    for (int mf = 0; mf < 4; ++mf)
#pragma unroll
      for (int rg = 0; rg < 4; ++rg) {
        const int m  = mf * 16 + lg * 4 + rg;
        const int gm = ebase + m;
        if (gm < E) {
#pragma unroll
          for (int nf = 0; nf < 2; ++nf) {
            const int n = wv * 32 + nf * 16 + lm;
            e_out[(long long)gm * DD + n] = acc2[mf][nf][rg] + b2[nf];
          }
        }
      }
  }
}

// ---------------- CSR scatter-mean: wave per node ----------------
__global__ __launch_bounds__(256) void agg_kernel(const float* __restrict__ e_out,
                                                  const int* __restrict__ off,
                                                  const int* __restrict__ perm,
                                                  float* __restrict__ agg, int N) {
  const int wv   = threadIdx.x >> 6;
  const int lane = threadIdx.x & 63;
  const int nid  = blockIdx.x * 4 + wv;
  if (nid >= N) return;
  const int o0 = off[nid], o1 = off[nid + 1];
  float ax = 0.f, ay = 0.f;
  for (int j = o0; j < o1; ++j) {
    const int r = perm[j];
    const float2 v = *reinterpret_cast<const float2*>(e_out + (long long)r * DD + (lane << 1));
    ax += v.x; ay += v.y;
  }
  const int deg = o1 - o0;
  const float inv = deg > 0 ? 1.f / (float)deg : 0.f;
  float2 o; o.x = ax * inv; o.y = ay * inv;
  *reinterpret_cast<float2*>(agg + (long long)nid * DD + (lane << 1)) = o;
}

// ---------------- node MLP ----------------
__global__ __launch_bounds__(256, 2) void node_mlp_kernel(
    const float* __restrict__ x,
    const float* __restrict__ Wn1,   // [256][128]
    const float* __restrict__ bn1,
    const float* __restrict__ Wn2,   // [128][128]
    const float* __restrict__ bn2,
    float* __restrict__ xout,        // in: agg mean, out: x_out
    int N)
{
  __shared__ __align__(16) unsigned short A_lds[64][264];
  __shared__ __align__(16) unsigned short h_lds[64][136];

  const int tid  = threadIdx.x;
  const int wv   = tid >> 6;
  const int lane = tid & 63;
  const int lg   = lane >> 4;
  const int lm   = lane & 15;

  bf16x8 w1f[8][2];
  bf16x8 w2f[4][2];
  float b1[2], b2[2];
#pragma unroll
  for (int nf = 0; nf < 2; ++nf) {
    const int n = wv * 32 + nf * 16 + lm;
    b1[nf] = bn1[n];
    b2[nf] = bn2[n];
#pragma unroll
    for (int kb = 0; kb < 8; ++kb) {
      bf16x8 f;
#pragma unroll
      for (int j = 0; j < 8; ++j)
        f[j] = (short)f2b(Wn1[(kb * 32 + lg * 8 + j) * DD + n]);
      w1f[kb][nf] = f;
    }
#pragma unroll
    for (int kb = 0; kb < 4; ++kb) {
      bf16x8 f;
#pragma unroll
      for (int j = 0; j < 8; ++j)
        f[j] = (short)f2b(Wn2[(kb * 32 + lg * 8 + j) * DD + n]);
      w2f[kb][nf] = f;
    }
  }

  const int ntiles = (N + 63) >> 6;
  for (int tile = blockIdx.x; tile < ntiles; tile += gridDim.x) {
    const int nbase = tile << 6;
    __syncthreads();

    // ---- stage A = [x | agg] as bf16 (agg already mean) ----
#pragma unroll
    for (int it = 0; it < 16; ++it) {
      const int q = tid + it * 256;
      const int r = q >> 6;
      const int c = q & 63;
      int gr = nbase + r;
      if (gr >= N) gr = N - 1;
      float4 v;
      if (c < 32) v = *reinterpret_cast<const float4*>(x + (long long)gr * DD + (c << 2));
      else        v = *reinterpret_cast<const float4*>(xout + (long long)gr * DD + ((c - 32) << 2));
      unsigned short* dst = &A_lds[r][c << 2];
      dst[0] = f2b(v.x); dst[1] = f2b(v.y); dst[2] = f2b(v.z); dst[3] = f2b(v.w);
    }
    __syncthreads();

    f32x4 acc[4][2];
#pragma unroll
    for (int mf = 0; mf < 4; ++mf)
#pragma unroll
      for (int nf = 0; nf < 2; ++nf)
        acc[mf][nf] = (f32x4){0.f, 0.f, 0.f, 0.f};

#pragma unroll
    for (int kb = 0; kb < 8; ++kb) {
      bf16x8 a[4];
#pragma unroll
      for (int mf = 0; mf < 4; ++mf)
        a[mf] = *reinterpret_cast<const bf16x8*>(&A_lds[mf * 16 + lm][kb * 32 + lg * 8]);
#pragma unroll
      for (int mf = 0; mf < 4; ++mf)
#pragma unroll
        for (int nf = 0; nf < 2; ++nf)
          acc[mf][nf] = __builtin_amdgcn_mfma_f32_16x16x32_bf16(a[mf], w1f[kb][nf], acc[mf][nf], 0, 0, 0);
    }

#pragma unroll
    for (int mf = 0; mf < 4; ++mf)
#pragma unroll
      for (int nf = 0; nf < 2; ++nf)
#pragma unroll
        for (int rg = 0; rg < 4; ++rg) {
          const int m = mf * 16 + lg * 4 + rg;
          const int n = wv * 32 + nf * 16 + lm;
          float v = acc[mf][nf][rg] + b1[nf];
          h_lds[m][n] = f2b(v > 0.f ? v : 0.f);
        }
    __syncthreads();

    f32x4 acc2[4][2];
#pragma unroll
    for (int mf = 0; mf < 4; ++mf)
#pragma unroll
      for (int nf = 0; nf < 2; ++nf)
        acc2[mf][nf] = (f32x4){0.f, 0.f, 0.f, 0.f};

#pragma unroll
    for (int kb = 0; kb < 4; ++kb) {
      bf16x8 a[4];
#pragma unroll
      for (int mf = 0; mf < 4; ++mf)
        a[mf] = *reinterpret_cast<const bf16x8*>(&h_lds[mf * 16 + lm][kb * 32 + lg * 8]);
#pragma unroll
      for (int mf = 0; mf < 4; ++mf)
#pragma unroll
        for (int nf = 0; nf < 2; ++nf)
          acc2[mf][nf] = __builtin_amdgcn_mfma_f32_16x16x32_bf16(a[mf], w2f[kb][nf], acc2[mf][nf], 0, 0, 0);
    }

#pragma unroll
    for (int mf = 0; mf < 4; ++mf)
#pragma unroll
      for (int rg = 0; rg < 4; ++rg) {
        const int m  = mf * 16 + lg * 4 + rg;
        const int gm = nbase + m;
        if (gm < N) {
#pragma unroll
          for (int nf = 0; nf < 2; ++nf) {
            const int n = wv * 32 + nf * 16 + lm;
            xout[(long long)gm * DD + n] = acc2[mf][nf][rg] + b2[nf];
          }
        }
      }
  }
}

extern "C" void kernel_launch(void* const* d_in, const int* in_sizes, int n_in,
                              void* d_out, int out_size, void* d_ws, size_t ws_size,
                              hipStream_t stream) {
  const float* x   = (const float*)d_in[0];
  const int*   ei  = (const int*)d_in[1];
  const float* ea  = (const float*)d_in[2];
  const float* We1 = (const float*)d_in[3];
  const float* be1 = (const float*)d_in[4];
  const float* We2 = (const float*)d_in[5];
  const float* be2 = (const float*)d_in[6];
  const float* Wn1 = (const float*)d_in[7];
  const float* bn1 = (const float*)d_in[8];
  const float* Wn2 = (const float*)d_in[9];
  const float* bn2 = (const float*)d_in[10];

  const int N = in_sizes[0] / DD;   // 50000
  const int E = in_sizes[2] / DD;   // 600000

  float* out   = (float*)d_out;
  float* xout  = out;                    // x_out; doubles as agg (mean) scratch
  float* e_out = out + (size_t)N * DD;   // e output

  int* cnt  = (int*)d_ws;                // N
  int* off  = cnt + N;                   // N+1
  int* cur  = off + N + 1;               // N
  int* perm = cur + N;                   // E
  int* bsum = perm + E;                  // <=64

  const int SCAN_B = (N + 1023) / 1024;  // 49

  hipMemsetAsync(cnt, 0, (size_t)N * sizeof(int), stream);

  count_kernel<<<(E + 255) / 256, 256, 0, stream>>>(ei, cnt, E);
  scan_a<<<SCAN_B, 256, 0, stream>>>(cnt, off, bsum, N);
  scan_b<<<1, 64, 0, stream>>>(bsum, SCAN_B);
  scan_c<<<SCAN_B, 256, 0, stream>>>(off, cur, bsum, N, E);
  fill_kernel<<<(E + 255) / 256, 256, 0, stream>>>(ei, cur, perm, E);

  edge_mlp_kernel<<<2048, 256, 0, stream>>>(x, ei, ea, We1, be1, We2, be2, e_out, E);

  agg_kernel<<<(N + 3) / 4, 256, 0, stream>>>(e_out, off, perm, xout, N);

  const int node_tiles = (N + 63) / 64;
  node_mlp_kernel<<<node_tiles, 256, 0, stream>>>(x, Wn1, bn1, Wn2, bn2, xout, N);
}

// Round 3
// 385.189 us; speedup vs baseline: 2.9631x; 1.6458x over previous
//
#include <hip/hip_runtime.h>
#include <hip/hip_bf16.h>

#define DD 128

typedef short bf16x8 __attribute__((ext_vector_type(8)));
typedef float f32x4 __attribute__((ext_vector_type(4)));

__device__ __forceinline__ unsigned short f2b(float f) {
  unsigned int u = __float_as_uint(f);
  u = u + 0x7FFFu + ((u >> 16) & 1u);
  return (unsigned short)(u >> 16);
}

// async global->LDS 16B: per-lane global src, wave-uniform LDS dest (+lane*16)
#define GLDS16(gp, lp) __builtin_amdgcn_global_load_lds( \
    (const __attribute__((address_space(1))) unsigned int*)(const void*)(gp), \
    (__attribute__((address_space(3))) unsigned int*)(void*)(lp), 16, 0, 0)

// ---------------- x f32 -> bf16 ----------------
__global__ __launch_bounds__(256) void cvt_x_kernel(const float* __restrict__ x,
                                                    unsigned short* __restrict__ xb, int n4) {
  const int i = blockIdx.x * 256 + threadIdx.x;
  if (i < n4) {
    const float4 v = reinterpret_cast<const float4*>(x)[i];
    ushort4 o;
    o.x = f2b(v.x); o.y = f2b(v.y); o.z = f2b(v.z); o.w = f2b(v.w);
    reinterpret_cast<ushort4*>(xb)[i] = o;
  }
}

// ---------------- per-node in-degree ----------------
__global__ void count_kernel(const int* __restrict__ ei, int* __restrict__ cnt, int E) {
  int i = blockIdx.x * blockDim.x + threadIdx.x;
  if (i < E) atomicAdd(&cnt[ei[E + i]], 1);
}

// ---------------- prefix scan (3 kernels) ----------------
__global__ __launch_bounds__(256) void scan_a(const int* __restrict__ cnt,
                                              int* __restrict__ off,
                                              int* __restrict__ bsum, int N) {
  __shared__ int wsum[4];
  const int t = threadIdx.x;
  const int i0 = blockIdx.x * 1024 + t * 4;
  int4 v = {0, 0, 0, 0};
  if (i0 + 3 < N) v = *reinterpret_cast<const int4*>(cnt + i0);
  else {
    if (i0 < N)     v.x = cnt[i0];
    if (i0 + 1 < N) v.y = cnt[i0 + 1];
    if (i0 + 2 < N) v.z = cnt[i0 + 2];
    if (i0 + 3 < N) v.w = cnt[i0 + 3];
  }
  const int s1 = v.x, s2 = s1 + v.y, s3 = s2 + v.z, tot = s3 + v.w;
  const int lane = t & 63, wv = t >> 6;
  int sc = tot;
#pragma unroll
  for (int d = 1; d < 64; d <<= 1) {
    int u = __shfl_up(sc, d);
    if (lane >= d) sc += u;
  }
  if (lane == 63) wsum[wv] = sc;
  __syncthreads();
  int wpre = 0;
  for (int w = 0; w < wv; ++w) wpre += wsum[w];
  const int excl = wpre + sc - tot;
  if (i0 < N)     off[i0]     = excl;
  if (i0 + 1 < N) off[i0 + 1] = excl + s1;
  if (i0 + 2 < N) off[i0 + 2] = excl + s2;
  if (i0 + 3 < N) off[i0 + 3] = excl + s3;
  if (t == 255) bsum[blockIdx.x] = wpre + sc;
}

__global__ void scan_b(int* __restrict__ bsum, int B) {
  const int t = threadIdx.x;
  const int v0 = (t < B) ? bsum[t] : 0;
  int v = v0;
#pragma unroll
  for (int d = 1; d < 64; d <<= 1) {
    int u = __shfl_up(v, d);
    if (t >= d) v += u;
  }
  if (t < B) bsum[t] = v - v0;
}

__global__ __launch_bounds__(256) void scan_c(int* __restrict__ off, int* __restrict__ cur,
                                              const int* __restrict__ bsum, int N, int E) {
  const int t = threadIdx.x;
  const int add = bsum[blockIdx.x];
  const int i0 = blockIdx.x * 1024 + t * 4;
#pragma unroll
  for (int k = 0; k < 4; ++k) {
    const int i = i0 + k;
    if (i < N) {
      const int o = off[i] + add;
      off[i] = o;
      cur[i] = o;
    }
  }
  if (blockIdx.x == 0 && t == 0) off[N] = E;
}

__global__ void fill_kernel(const int* __restrict__ ei, int* __restrict__ cur,
                            int* __restrict__ perm, int E) {
  int i = blockIdx.x * blockDim.x + threadIdx.x;
  if (i < E) {
    const int d = ei[E + i];
    const int pos = atomicAdd(&cur[d], 1);
    perm[pos] = i;
  }
}

// ---------------- edge MLP: async-gather staging + MFMA ----------------
// E is a multiple of 64 (600000 = 9375*64) — no tail handling.
__global__ __launch_bounds__(256, 2) void edge_mlp_kernel(
    const unsigned short* __restrict__ xb,   // [N][128] bf16
    const int* __restrict__ ei,              // [2][E]
    const float* __restrict__ ea,            // [E][128] f32
    const float* __restrict__ We1,
    const float* __restrict__ be1,
    const float* __restrict__ We2,
    const float* __restrict__ be2,
    float* __restrict__ e_out,               // [E][128] f32
    int E)
{
  // x blocks are staged by global_load_lds (linear dest, pre-swizzled source):
  // LDS[r][chunk j] holds global chunk (j ^ (r&7)); reads apply the same XOR.
  __shared__ __align__(16) unsigned short xs_lds[64][128];
  __shared__ __align__(16) unsigned short xd_lds[64][128];
  __shared__ __align__(16) unsigned short ea_lds[64][128];
  __shared__ __align__(16) unsigned short h_lds[64][136];
  __shared__ int srcs[64], dsts[64];

  const int tid  = threadIdx.x;
  const int wv   = tid >> 6;
  const int lane = tid & 63;
  const int lg   = lane >> 4;
  const int lm   = lane & 15;

  // ---- weight fragments in registers ----
  bf16x8 w1f[12][2];
  bf16x8 w2f[4][2];
  float b1[2], b2[2];
#pragma unroll
  for (int nf = 0; nf < 2; ++nf) {
    const int n = wv * 32 + nf * 16 + lm;
    b1[nf] = be1[n];
    b2[nf] = be2[n];
#pragma unroll
    for (int kb = 0; kb < 12; ++kb) {
      bf16x8 f;
#pragma unroll
      for (int j = 0; j < 8; ++j)
        f[j] = (short)f2b(We1[(kb * 32 + lg * 8 + j) * DD + n]);
      w1f[kb][nf] = f;
    }
#pragma unroll
    for (int kb = 0; kb < 4; ++kb) {
      bf16x8 f;
#pragma unroll
      for (int j = 0; j < 8; ++j)
        f[j] = (short)f2b(We2[(kb * 32 + lg * 8 + j) * DD + n]);
      w2f[kb][nf] = f;
    }
  }

  const int ntiles = E >> 6;
  for (int tile = blockIdx.x; tile < ntiles; tile += gridDim.x) {
    const int ebase = tile << 6;
    __syncthreads();  // previous tile's LDS readers done

    // ---- preload this tile's 128 indices ----
    if (tid < 64)       srcs[tid]      = ei[ebase + tid];
    else if (tid < 128) dsts[tid - 64] = ei[E + ebase + tid - 64];
    __syncthreads();

    // ---- async x gathers: each wave stages 16 rows of xs and xd ----
    {
#pragma unroll
      for (int wl = 0; wl < 4; ++wl) {
        const int r0 = wv * 16 + wl * 4;
        const int r  = r0 + (lane >> 4);
        const int ch = (lane & 15) ^ (r & 7);
        GLDS16(xb + (size_t)srcs[r] * DD + ch * 8, &xs_lds[r0][0]);
        GLDS16(xb + (size_t)dsts[r] * DD + ch * 8, &xd_lds[r0][0]);
      }
    }

    // ---- ea: coalesced f32 loads -> bf16 -> swizzled b128 LDS writes ----
    {
      float4 va[4], vb[4];
#pragma unroll
      for (int it = 0; it < 4; ++it) {
        const int q = tid + it * 256;
        const int r = q >> 4;
        const int c = q & 15;
        const float* p = ea + (size_t)(ebase + r) * DD + c * 8;
        va[it] = *reinterpret_cast<const float4*>(p);
        vb[it] = *reinterpret_cast<const float4*>(p + 4);
      }
#pragma unroll
      for (int it = 0; it < 4; ++it) {
        const int q = tid + it * 256;
        const int r = q >> 4;
        const int c = q & 15;
        bf16x8 o;
        o[0] = (short)f2b(va[it].x); o[1] = (short)f2b(va[it].y);
        o[2] = (short)f2b(va[it].z); o[3] = (short)f2b(va[it].w);
        o[4] = (short)f2b(vb[it].x); o[5] = (short)f2b(vb[it].y);
        o[6] = (short)f2b(vb[it].z); o[7] = (short)f2b(vb[it].w);
        *reinterpret_cast<bf16x8*>(&ea_lds[r][(c ^ (r & 7)) * 8]) = o;
      }
    }
    __syncthreads();  // drains vmcnt (incl. global_load_lds) + lgkm

    // ---- layer 1: h = relu(A @ We1 + be1), K = 384 ----
    f32x4 acc[4][2];
#pragma unroll
    for (int mf = 0; mf < 4; ++mf)
#pragma unroll
      for (int nf = 0; nf < 2; ++nf)
        acc[mf][nf] = (f32x4){0.f, 0.f, 0.f, 0.f};

#pragma unroll
    for (int kb = 0; kb < 12; ++kb) {
      const unsigned short (*blk)[128] = (kb < 4) ? xs_lds : (kb < 8) ? xd_lds : ea_lds;
      const int kl = kb & 3;
      bf16x8 a[4];
#pragma unroll
      for (int mf = 0; mf < 4; ++mf) {
        const int r = mf * 16 + lm;
        a[mf] = *reinterpret_cast<const bf16x8*>(&blk[r][((kl * 4 + lg) ^ (r & 7)) * 8]);
      }
#pragma unroll
      for (int mf = 0; mf < 4; ++mf)
#pragma unroll
        for (int nf = 0; nf < 2; ++nf)
          acc[mf][nf] = __builtin_amdgcn_mfma_f32_16x16x32_bf16(a[mf], w1f[kb][nf], acc[mf][nf], 0, 0, 0);
    }

#pragma unroll
    for (int mf = 0; mf < 4; ++mf)
#pragma unroll
      for (int nf = 0; nf < 2; ++nf)
#pragma unroll
        for (int rg = 0; rg < 4; ++rg) {
          const int m = mf * 16 + lg * 4 + rg;
          const int n = wv * 32 + nf * 16 + lm;
          float v = acc[mf][nf][rg] + b1[nf];
          h_lds[m][n] = f2b(v > 0.f ? v : 0.f);
        }
    __syncthreads();

    // ---- layer 2: e = h @ We2 + be2 ----
    f32x4 acc2[4][2];
#pragma unroll
    for (int mf = 0; mf < 4; ++mf)
#pragma unroll
      for (int nf = 0; nf < 2; ++nf)
        acc2[mf][nf] = (f32x4){0.f, 0.f, 0.f, 0.f};

#pragma unroll
    for (int kb = 0; kb < 4; ++kb) {
      bf16x8 a[4];
#pragma unroll
      for (int mf = 0; mf < 4; ++mf)
        a[mf] = *reinterpret_cast<const bf16x8*>(&h_lds[mf * 16 + lm][kb * 32 + lg * 8]);
#pragma unroll
      for (int mf = 0; mf < 4; ++mf)
#pragma unroll
        for (int nf = 0; nf < 2; ++nf)
          acc2[mf][nf] = __builtin_amdgcn_mfma_f32_16x16x32_bf16(a[mf], w2f[kb][nf], acc2[mf][nf], 0, 0, 0);
    }

    // ---- epilogue: write e ----
#pragma unroll
    for (int mf = 0; mf < 4; ++mf)
#pragma unroll
      for (int rg = 0; rg < 4; ++rg) {
        const int gm = ebase + mf * 16 + lg * 4 + rg;
#pragma unroll
        for (int nf = 0; nf < 2; ++nf) {
          const int n = wv * 32 + nf * 16 + lm;
          e_out[(size_t)gm * DD + n] = acc2[mf][nf][rg] + b2[nf];
        }
      }
  }
}

// ---------------- CSR scatter-mean: wave per node, 4-deep unroll ----------------
__global__ __launch_bounds__(256) void agg_kernel(const float* __restrict__ e_out,
                                                  const int* __restrict__ off,
                                                  const int* __restrict__ perm,
                                                  float* __restrict__ agg, int N) {
  const int wv   = threadIdx.x >> 6;
  const int lane = threadIdx.x & 63;
  const int nid  = blockIdx.x * 4 + wv;
  if (nid >= N) return;
  const int o0 = off[nid], o1 = off[nid + 1];
  float2 s0 = {0.f, 0.f}, s1 = {0.f, 0.f}, s2 = {0.f, 0.f}, s3 = {0.f, 0.f};
  int j = o0;
  for (; j + 4 <= o1; j += 4) {
    const int r0 = perm[j], r1 = perm[j + 1], r2 = perm[j + 2], r3 = perm[j + 3];
    const float2 v0 = *reinterpret_cast<const float2*>(e_out + (size_t)r0 * DD + (lane << 1));
    const float2 v1 = *reinterpret_cast<const float2*>(e_out + (size_t)r1 * DD + (lane << 1));
    const float2 v2 = *reinterpret_cast<const float2*>(e_out + (size_t)r2 * DD + (lane << 1));
    const float2 v3 = *reinterpret_cast<const float2*>(e_out + (size_t)r3 * DD + (lane << 1));
    s0.x += v0.x; s0.y += v0.y;
    s1.x += v1.x; s1.y += v1.y;
    s2.x += v2.x; s2.y += v2.y;
    s3.x += v3.x; s3.y += v3.y;
  }
  for (; j < o1; ++j) {
    const int r = perm[j];
    const float2 v = *reinterpret_cast<const float2*>(e_out + (size_t)r * DD + (lane << 1));
    s0.x += v.x; s0.y += v.y;
  }
  const int deg = o1 - o0;
  const float inv = deg > 0 ? 1.f / (float)deg : 0.f;
  float2 o;
  o.x = (s0.x + s1.x + s2.x + s3.x) * inv;
  o.y = (s0.y + s1.y + s2.y + s3.y) * inv;
  *reinterpret_cast<float2*>(agg + (size_t)nid * DD + (lane << 1)) = o;
}

// ---------------- node MLP ----------------
__global__ __launch_bounds__(256, 2) void node_mlp_kernel(
    const float* __restrict__ x,
    const float* __restrict__ Wn1,
    const float* __restrict__ bn1,
    const float* __restrict__ Wn2,
    const float* __restrict__ bn2,
    float* __restrict__ xout,        // in: agg mean, out: x_out
    int N)
{
  __shared__ __align__(16) unsigned short A_lds[64][264];
  __shared__ __align__(16) unsigned short h_lds[64][136];

  const int tid  = threadIdx.x;
  const int wv   = tid >> 6;
  const int lane = tid & 63;
  const int lg   = lane >> 4;
  const int lm   = lane & 15;

  bf16x8 w1f[8][2];
  bf16x8 w2f[4][2];
  float b1[2], b2[2];
#pragma unroll
  for (int nf = 0; nf < 2; ++nf) {
    const int n = wv * 32 + nf * 16 + lm;
    b1[nf] = bn1[n];
    b2[nf] = bn2[n];
#pragma unroll
    for (int kb = 0; kb < 8; ++kb) {
      bf16x8 f;
#pragma unroll
      for (int j = 0; j < 8; ++j)
        f[j] = (short)f2b(Wn1[(kb * 32 + lg * 8 + j) * DD + n]);
      w1f[kb][nf] = f;
    }
#pragma unroll
    for (int kb = 0; kb < 4; ++kb) {
      bf16x8 f;
#pragma unroll
      for (int j = 0; j < 8; ++j)
        f[j] = (short)f2b(Wn2[(kb * 32 + lg * 8 + j) * DD + n]);
      w2f[kb][nf] = f;
    }
  }

  const int ntiles = (N + 63) >> 6;
  for (int tile = blockIdx.x; tile < ntiles; tile += gridDim.x) {
    const int nbase = tile << 6;
    __syncthreads();

#pragma unroll
    for (int it = 0; it < 16; ++it) {
      const int q = tid + it * 256;
      const int r = q >> 6;
      const int c = q & 63;
      int gr = nbase + r;
      if (gr >= N) gr = N - 1;
      float4 v;
      if (c < 32) v = *reinterpret_cast<const float4*>(x + (size_t)gr * DD + (c << 2));
      else        v = *reinterpret_cast<const float4*>(xout + (size_t)gr * DD + ((c - 32) << 2));
      unsigned short* dst = &A_lds[r][c << 2];
      dst[0] = f2b(v.x); dst[1] = f2b(v.y); dst[2] = f2b(v.z); dst[3] = f2b(v.w);
    }
    __syncthreads();

    f32x4 acc[4][2];
#pragma unroll
    for (int mf = 0; mf < 4; ++mf)
#pragma unroll
      for (int nf = 0; nf < 2; ++nf)
        acc[mf][nf] = (f32x4){0.f, 0.f, 0.f, 0.f};

#pragma unroll
    for (int kb = 0; kb < 8; ++kb) {
      bf16x8 a[4];
#pragma unroll
      for (int mf = 0; mf < 4; ++mf)
        a[mf] = *reinterpret_cast<const bf16x8*>(&A_lds[mf * 16 + lm][kb * 32 + lg * 8]);
#pragma unroll
      for (int mf = 0; mf < 4; ++mf)
#pragma unroll
        for (int nf = 0; nf < 2; ++nf)
          acc[mf][nf] = __builtin_amdgcn_mfma_f32_16x16x32_bf16(a[mf], w1f[kb][nf], acc[mf][nf], 0, 0, 0);
    }

#pragma unroll
    for (int mf = 0; mf < 4; ++mf)
#pragma unroll
      for (int nf = 0; nf < 2; ++nf)
#pragma unroll
        for (int rg = 0; rg < 4; ++rg) {
          const int m = mf * 16 + lg * 4 + rg;
          const int n = wv * 32 + nf * 16 + lm;
          float v = acc[mf][nf][rg] + b1[nf];
          h_lds[m][n] = f2b(v > 0.f ? v : 0.f);
        }
    __syncthreads();

    f32x4 acc2[4][2];
#pragma unroll
    for (int mf = 0; mf < 4; ++mf)
#pragma unroll
      for (int nf = 0; nf < 2; ++nf)
        acc2[mf][nf] = (f32x4){0.f, 0.f, 0.f, 0.f};

#pragma unroll
    for (int kb = 0; kb < 4; ++kb) {
      bf16x8 a[4];
#pragma unroll
      for (int mf = 0; mf < 4; ++mf)
        a[mf] = *reinterpret_cast<const bf16x8*>(&h_lds[mf * 16 + lm][kb * 32 + lg * 8]);
#pragma unroll
      for (int mf = 0; mf < 4; ++mf)
#pragma unroll
        for (int nf = 0; nf < 2; ++nf)
          acc2[mf][nf] = __builtin_amdgcn_mfma_f32_16x16x32_bf16(a[mf], w2f[kb][nf], acc2[mf][nf], 0, 0, 0);
    }

#pragma unroll
    for (int mf = 0; mf < 4; ++mf)
#pragma unroll
      for (int rg = 0; rg < 4; ++rg) {
        const int gm = nbase + mf * 16 + lg * 4 + rg;
        if (gm < N) {
#pragma unroll
          for (int nf = 0; nf < 2; ++nf) {
            const int n = wv * 32 + nf * 16 + lm;
            xout[(size_t)gm * DD + n] = acc2[mf][nf][rg] + b2[nf];
          }
        }
      }
  }
}

extern "C" void kernel_launch(void* const* d_in, const int* in_sizes, int n_in,
                              void* d_out, int out_size, void* d_ws, size_t ws_size,
                              hipStream_t stream) {
  const float* x   = (const float*)d_in[0];
  const int*   ei  = (const int*)d_in[1];
  const float* ea  = (const float*)d_in[2];
  const float* We1 = (const float*)d_in[3];
  const float* be1 = (const float*)d_in[4];
  const float* We2 = (const float*)d_in[5];
  const float* be2 = (const float*)d_in[6];
  const float* Wn1 = (const float*)d_in[7];
  const float* bn1 = (const float*)d_in[8];
  const float* Wn2 = (const float*)d_in[9];
  const float* bn2 = (const float*)d_in[10];

  const int N = in_sizes[0] / DD;   // 50000
  const int E = in_sizes[2] / DD;   // 600000

  float* out   = (float*)d_out;
  float* xout  = out;                    // x_out; early: x_bf16 scratch, then agg mean
  float* e_out = out + (size_t)N * DD;   // e output

  unsigned short* xb = (unsigned short*)xout;  // x as bf16 (overwritten by agg later)

  int* cnt  = (int*)d_ws;                // N
  int* off  = cnt + N;                   // N+1
  int* cur  = off + N + 1;               // N
  int* perm = cur + N;                   // E
  int* bsum = perm + E;                  // <=64

  const int SCAN_B = (N + 1023) / 1024;  // 49

  hipMemsetAsync(cnt, 0, (size_t)N * sizeof(int), stream);

  cvt_x_kernel<<<(N * DD / 4 + 255) / 256, 256, 0, stream>>>(x, xb, N * DD / 4);

  count_kernel<<<(E + 255) / 256, 256, 0, stream>>>(ei, cnt, E);
  scan_a<<<SCAN_B, 256, 0, stream>>>(cnt, off, bsum, N);
  scan_b<<<1, 64, 0, stream>>>(bsum, SCAN_B);
  scan_c<<<SCAN_B, 256, 0, stream>>>(off, cur, bsum, N, E);
  fill_kernel<<<(E + 255) / 256, 256, 0, stream>>>(ei, cur, perm, E);

  edge_mlp_kernel<<<2048, 256, 0, stream>>>(xb, ei, ea, We1, be1, We2, be2, e_out, E);

  agg_kernel<<<(N + 3) / 4, 256, 0, stream>>>(e_out, off, perm, xout, N);

  const int node_tiles = (N + 63) / 64;
  node_mlp_kernel<<<node_tiles, 256, 0, stream>>>(x, Wn1, bn1, Wn2, bn2, xout, N);
}